// Round 5
// baseline (349.528 us; speedup 1.0000x reference)
//
#include <hip/hip_runtime.h>
#include <hip/hip_bf16.h>

typedef _Float16 f16x8 __attribute__((ext_vector_type(8)));
typedef _Float16 f16x4 __attribute__((ext_vector_type(4)));
typedef float f32x4 __attribute__((ext_vector_type(4)));
typedef int i32x4 __attribute__((ext_vector_type(4)));

__device__ __forceinline__ float bf2f(unsigned short u) {
  union { unsigned int i; float f; } x; x.i = ((unsigned int)u) << 16; return x.f;
}
// clamp-to-finite fp16 convert: any upstream bug shows finite, not NaN
__device__ __forceinline__ _Float16 h16(float f) {
  return (_Float16)fminf(fmaxf(f, -60000.f), 60000.f);
}

// accurate -log(u): series for u near 1 (1-u exact by Sterbenz there)
__device__ __forceinline__ float neglog(float u) {
  if (u > 0.99f) {
    const float d = 1.0f - u;
    return d + 0.5f * d * d + (1.0f / 3.0f) * d * d * d;
  }
  return -__logf(u);
}

// plain butterfly sum across 64 lanes
__device__ __forceinline__ float wsum(float v) {
#pragma unroll
  for (int off = 1; off < 64; off <<= 1) v += __shfl_xor(v, off, 64);
  return v;
}

// St row-keyed XOR swizzle: element idx ^ ((row&7)<<3) (byte bits 4-6).
// Stride-1024 rows -> Phase-C b128 column reads bank-balanced; Phase-B
// accesses are row-uniform (constant XOR per instr) = unchanged.
__device__ __forceinline__ int sidx(int row, int col) {
  return ((row) * 1024 + (col)) ^ (((row) & 7) << 3);
}

// Per-wave dtype detection: every wave reads the same first 64 bf16-shorts
// of gumbel (even indices) and ballots -> identical flag in all waves, no
// LDS, no barrier, no separate kernel. 0 = bf16 inputs, 1 = fp32 inputs.
__device__ __forceinline__ int wave_flag(const unsigned short* __restrict__ g, int tid) {
  const float f = bf2f(g[(tid & 63) * 2]);
  const unsigned long long m = __ballot((f >= 8e-7f) && (f <= 1.0f));
  return (m == ~0ull) ? 0 : 1;
}

// ---------------------------------------------------------------------------
// Kernel 0: convert hidden + Wq/Wk/Wv to fp16 once.
// dst: [hid 2M | Wq 1M | Wk 1M | Wv 1M] halves.
// ---------------------------------------------------------------------------
__global__ __launch_bounds__(256) void cvt_inputs(
    const void* __restrict__ h, const void* __restrict__ wq,
    const void* __restrict__ wk, const void* __restrict__ wv,
    const unsigned short* __restrict__ gum, _Float16* __restrict__ dst)
{
  const int flg = wave_flag(gum, threadIdx.x);
  const int y = blockIdx.y;
  const int n = (y == 0) ? (2 * 1024 * 1024) : (1024 * 1024);
  const int idx = (blockIdx.x * 256 + threadIdx.x) * 4;
  if (idx >= n) return;
  const void* src = (y == 0) ? h : (y == 1) ? wq : (y == 2) ? wk : wv;
  const size_t base = (y == 0) ? 0 : (size_t)(2 * 1024 * 1024) + (size_t)(y - 1) * 1024 * 1024;
  f16x4 o;
  if (flg) {
    f32x4 v = *(const f32x4*)((const float*)src + idx);
#pragma unroll
    for (int j = 0; j < 4; j++) o[j] = h16(v[j]);
  } else {
    union { unsigned long long q; unsigned short u[4]; } ld;
    ld.q = *(const unsigned long long*)((const unsigned short*)src + idx);
#pragma unroll
    for (int j = 0; j < 4; j++) o[j] = h16(bf2f(ld.u[j]));
  }
  *(f16x4*)(dst + base + idx) = o;
}

// ---------------------------------------------------------------------------
// Kernel 1: QKV projection on pre-converted fp16. NT gemm 2048 x 3072 x 1024.
// 64x128 tiles, BK=64 -> 768 blocks (3/CU) for latency hiding.
// ---------------------------------------------------------------------------
__global__ __launch_bounds__(256) void qkv_gemm(
    const _Float16* __restrict__ cvt,   // [hid | Wq | Wk | Wv]
    const unsigned short* __restrict__ bq, const unsigned short* __restrict__ bk,
    const unsigned short* __restrict__ bv,
    const unsigned short* __restrict__ gum,
    _Float16* __restrict__ q_ws, _Float16* __restrict__ k_ws,
    _Float16* __restrict__ v_ws)
{
  __shared__ _Float16 At[64][72];   // 64 x 64 fp16, +8 pad
  __shared__ _Float16 Bt[128][72];  // 128 x 64 fp16, +8 pad
  const int flg = wave_flag(gum, threadIdx.x);
  const int tn = blockIdx.x;        // 32 M-tiles of 64 rows
  const int to = blockIdx.y;        // 24 N-tiles of 128 cols over [q|k|v]
  const int mat = to >> 3;          // 0=q 1=k 2=v
  const int o0 = (to & 7) * 128;
  const _Float16* hid16 = cvt;
  const _Float16* W16 = cvt + (size_t)(2 * 1024 * 1024) + (size_t)mat * 1024 * 1024;
  const unsigned short* bias = (mat == 0) ? bq : (mat == 1) ? bk : bv;
  const float* biasf = (const float*)bias;
  const int tid = threadIdx.x;
  const int lane = tid & 63, wave = tid >> 6;
  const int wm = (wave >> 1) * 32, wn = (wave & 1) * 64;  // 2x2 quadrants 32x64
  const int lm = lane & 15, lq = lane >> 4;
  f32x4 acc[2][4] = {};

  for (int kc = 0; kc < 1024; kc += 64) {
    __syncthreads();
#pragma unroll
    for (int i = 0; i < 2; i++) {  // A: 64 rows x 8 chunks of 16B
      const int cid = i * 256 + tid;
      const int r = cid >> 3, c8 = cid & 7;
      *(i32x4*)(&At[r][c8 * 8]) =
          *(const i32x4*)(hid16 + (size_t)(tn * 64 + r) * 1024 + kc + c8 * 8);
    }
#pragma unroll
    for (int i = 0; i < 4; i++) {  // B: 128 rows x 8 chunks of 16B
      const int cid = i * 256 + tid;
      const int r = cid >> 3, c8 = cid & 7;
      *(i32x4*)(&Bt[r][c8 * 8]) =
          *(const i32x4*)(W16 + (size_t)(o0 + r) * 1024 + kc + c8 * 8);
    }
    __syncthreads();
    f16x8 af[2][2], bfr[4][2];
#pragma unroll
    for (int mt = 0; mt < 2; mt++)
#pragma unroll
      for (int k2 = 0; k2 < 2; k2++)
        af[mt][k2] = *(const f16x8*)(&At[wm + mt * 16 + lm][k2 * 32 + lq * 8]);
#pragma unroll
    for (int nt = 0; nt < 4; nt++)
#pragma unroll
      for (int k2 = 0; k2 < 2; k2++)
        bfr[nt][k2] = *(const f16x8*)(&Bt[wn + nt * 16 + lm][k2 * 32 + lq * 8]);
#pragma unroll
    for (int mt = 0; mt < 2; mt++)
#pragma unroll
      for (int nt = 0; nt < 4; nt++)
#pragma unroll
        for (int k2 = 0; k2 < 2; k2++)
          acc[mt][nt] = __builtin_amdgcn_mfma_f32_16x16x32_f16(
              af[mt][k2], bfr[nt][k2], acc[mt][nt], 0, 0, 0);
  }

  // epilogue: C/D layout col=lane&15, row=quad*4+reg
  _Float16* dst = (mat == 0) ? q_ws : (mat == 1) ? k_ws : v_ws;
#pragma unroll
  for (int nt = 0; nt < 4; nt++) {
    const int ol = o0 + wn + nt * 16 + lm;
    const float bias_v = flg ? biasf[ol] : bf2f(bias[ol]);
    const int hh = ol >> 6, dd = ol & 63;
#pragma unroll
    for (int mt = 0; mt < 2; mt++) {
#pragma unroll
      for (int rg = 0; rg < 4; rg++) {
        const int n = tn * 64 + wm + mt * 16 + lq * 4 + rg;  // b*1024+s
        const int b = n >> 10, s = n & 1023;
        dst[((size_t)(b * 16 + hh) * 1024 + s) * 64 + dd] = h16(acc[mt][nt][rg] + bias_v);
      }
    }
  }
}

// ---------------------------------------------------------------------------
// Kernel 2: transpose v [bh][s][64] -> vT [bh][64][s] via LDS 64x64 tiles,
// plus (grid y==32) dist_emb -> fp16 conversion. One launch instead of two.
// ---------------------------------------------------------------------------
__global__ __launch_bounds__(256) void transpose_v_emb(
    const _Float16* __restrict__ v_ws, _Float16* __restrict__ vT_ws,
    const void* __restrict__ de, const unsigned short* __restrict__ gum,
    _Float16* __restrict__ e16)
{
  __shared__ unsigned short Tt[64 * 66];
  const int tid = threadIdx.x;

  if (blockIdx.y == 32) {
    // dist_emb conversion: 2047*64 = 131008 halves = 32752 vec4 chunks
    const int flg = wave_flag(gum, tid);
    for (int c = blockIdx.x * 256 + tid; c < 32752; c += 16 * 256) {
      const int idx = c * 4;
      f16x4 o;
      if (flg) {
        f32x4 v = *(const f32x4*)((const float*)de + idx);
#pragma unroll
        for (int j = 0; j < 4; j++) o[j] = h16(v[j]);
      } else {
        union { unsigned long long q; unsigned short u[4]; } ld;
        ld.q = *(const unsigned long long*)((const unsigned short*)de + idx);
#pragma unroll
        for (int j = 0; j < 4; j++) o[j] = h16(bf2f(ld.u[j]));
      }
      *(f16x4*)(e16 + idx) = o;
    }
    return;
  }

  const int st = blockIdx.x;   // 16 s-tiles
  const int bh = blockIdx.y;   // 32
  const unsigned short* src = (const unsigned short*)(v_ws + (size_t)bh * 65536);
#pragma unroll
  for (int i = 0; i < 2; i++) {
    const int cid = i * 256 + tid;
    const int r = cid >> 3, c8 = cid & 7;   // row in tile, 8-half chunk
    union { i32x4 v; unsigned int w[4]; } ld;
    ld.v = *(const i32x4*)(src + (size_t)(st * 64 + r) * 64 + c8 * 8);
#pragma unroll
    for (int w = 0; w < 4; w++)
      *(unsigned int*)(&Tt[r * 66 + c8 * 8 + w * 2]) = ld.w[w];
  }
  __syncthreads();
  const int d = tid >> 2, sc = (tid & 3) * 16;
  unsigned short us[16];
#pragma unroll
  for (int j = 0; j < 16; j++) us[j] = Tt[(sc + j) * 66 + d];
  unsigned short* dst = (unsigned short*)(vT_ws + (size_t)bh * 65536 + (size_t)d * 1024 + st * 64 + sc);
#pragma unroll
  for (int w = 0; w < 4; w++)
    *(unsigned long long*)(dst + w * 4) = *(unsigned long long*)(us + w * 4);
}

// ---------------------------------------------------------------------------
// Kernel 3: fused scores + rel-pos + gumbel double-softmax + PV.
// One block of EIGHT waves (512 threads) per (b, h, 16-row l-tile).
// 2048 blocks.
//
// vs R4 (4 waves): same 16-row tile, same total work, but each wave's
// serial chain is HALVED and waves/CU doubles (4 blocks x 8 waves =
// 32 waves/CU = hardware cap; was ~13 measured). This attacks the
// latency-bound profile (all pipes <40% busy) directly with TLP.
//  - Phase A: chunks of 128 cols (8 waves x 16), 8 iters/wave (was 16).
//  - Phase B: 2 rows/wave (was 4), both prefetched before the barrier.
//  - Phase C: r-dim split in half across wave groups; partials combined
//    through a 4 KB LDS buffer (+1 barrier).
// VGPR must stay <=64 for 8 waves/SIMD (R4 measured 52 with more live
// state; launch_bounds(512,8) enforces).
// ---------------------------------------------------------------------------
__global__ __launch_bounds__(512, 8) void attn_kernel(
    const _Float16* __restrict__ q_ws, const _Float16* __restrict__ k_ws,
    const _Float16* __restrict__ vT_ws,
    const _Float16* __restrict__ e16,      // [2047][64] fp16
    const unsigned short* __restrict__ gumbel_u,
    const unsigned short* __restrict__ mask,
    float* __restrict__ out)
{
  __shared__ _Float16 St[16 * 1024];  // scores -> probs in place, 32768 B
  __shared__ float Cc[4 * 64 * 4];    // Phase-C partial ctx (half 1), 4 KB
  const int tid = threadIdx.x, wave = tid >> 6, lane = tid & 63;
  const int flg = wave_flag(gumbel_u, tid);
  const int blk = blockIdx.x;
  const int lt = blk & 63;
  const int bh = blk >> 6;
  const int b = bh >> 4, h = bh & 15;
  const int L = lt * 16;
  const _Float16* qp = q_ws + (size_t)bh * 65536;
  const _Float16* kp = k_ws + (size_t)bh * 65536;
  const _Float16* vp = vT_ws + (size_t)bh * 65536;
  const unsigned short* up = gumbel_u + (size_t)bh * 1024 * 1024;
  const float* upf = (const float*)gumbel_u + (size_t)bh * 1024 * 1024;
  const float* maskf = (const float*)mask;
  const int lm = lane & 15, lq = lane >> 4;
  const int rr = wave * 16 + lm;         // this wave's score column in [0,128)

  // Q tile A-fragments held for the whole block
  const f16x8 qa0 = *(const f16x8*)(qp + (L + lm) * 64 + lq * 8);
  const f16x8 qa1 = *(const f16x8*)(qp + (L + lm) * 64 + 32 + lq * 8);

  // ---- Phase A (no barriers): St = (Q.K^T + Q.E[l-r+1023])/8 + mask ----
  // 8 chunks of 128 columns; wave-private rel-pos via ds_bpermute.
  // j = base + (i+15-lm), base = L-R+1008-16*wave in [0,2016] for wave<8.
#pragma unroll 2
  for (int R = 0; R < 1024; R += 128) {
    const _Float16* krow = kp + (R + rr) * 64;
    const f16x8 kb0 = *(const f16x8*)(krow + lq * 8);
    const f16x8 kb1 = *(const f16x8*)(krow + 32 + lq * 8);
    const int base = L - R + 1008 - wave * 16;   // in [0, 2016]
    const int r0e = base + lm;                   // <= 2031, >= 0
    int r1e = base + 16 + lm;                    // <= 2047: clamp
    if (r1e > 2046) r1e = 2046;                  // o=31 never consumed
    const f16x8 e00 = *(const f16x8*)(e16 + (size_t)r0e * 64 + lq * 8);
    const f16x8 e01 = *(const f16x8*)(e16 + (size_t)r0e * 64 + 32 + lq * 8);
    const f16x8 e10 = *(const f16x8*)(e16 + (size_t)r1e * 64 + lq * 8);
    const f16x8 e11 = *(const f16x8*)(e16 + (size_t)r1e * 64 + 32 + lq * 8);
    const float mval = flg ? maskf[b * 1024 + R + rr] : bf2f(mask[b * 1024 + R + rr]);

    f32x4 aqk = {0.f, 0.f, 0.f, 0.f};
    aqk = __builtin_amdgcn_mfma_f32_16x16x32_f16(qa0, kb0, aqk, 0, 0, 0);
    aqk = __builtin_amdgcn_mfma_f32_16x16x32_f16(qa1, kb1, aqk, 0, 0, 0);
    f32x4 au0 = {0.f, 0.f, 0.f, 0.f}, au1 = {0.f, 0.f, 0.f, 0.f};
    au0 = __builtin_amdgcn_mfma_f32_16x16x32_f16(qa0, e00, au0, 0, 0, 0);
    au0 = __builtin_amdgcn_mfma_f32_16x16x32_f16(qa1, e01, au0, 0, 0, 0);
    au1 = __builtin_amdgcn_mfma_f32_16x16x32_f16(qa0, e10, au1, 0, 0, 0);
    au1 = __builtin_amdgcn_mfma_f32_16x16x32_f16(qa1, e11, au1, 0, 0, 0);

#pragma unroll
    for (int rg = 0; rg < 4; rg++) {
      const int o = lq * 4 + rg + 15 - lm;             // [0,30]
      const int idx = ((lane & 48) | (o & 15)) << 2;   // byte index for bpermute
      const float u0 = __int_as_float(
          __builtin_amdgcn_ds_bpermute(idx, __float_as_int(au0[rg])));
      const float u1 = __int_as_float(
          __builtin_amdgcn_ds_bpermute(idx, __float_as_int(au1[rg])));
      const float uval = (o >= 16) ? u1 : u0;
      St[sidx(lq * 4 + rg, R + rr)] = h16((aqk[rg] + uval) * 0.125f + mval);
    }
  }

  // ---- Phase B: max-free double softmax, 2 rows/wave, both prefetched ----
  const int i0 = wave * 2;
  f32x4 uA[4], uB[4];
  auto ldrow = [&](f32x4 (&dst)[4], int i) {
    if (flg) {
      const float* urf = upf + (size_t)(L + i) * 1024 + lane * 4;
#pragma unroll
      for (int c = 0; c < 4; c++) dst[c] = *(const f32x4*)(urf + c * 256);
    } else {
      const unsigned short* ur = up + (size_t)(L + i) * 1024 + lane * 4;
#pragma unroll
      for (int c = 0; c < 4; c++) {
        union { unsigned long long q; unsigned short u[4]; } ld;
        ld.q = *(const unsigned long long*)(ur + c * 256);
        f32x4 v;
#pragma unroll
        for (int j = 0; j < 4; j++) v[j] = bf2f(ld.u[j]);
        dst[c] = v;
      }
    }
  };
  auto dorow = [&](const f32x4 (&uv)[4], int i) {
    f16x4 sh[4];
#pragma unroll
    for (int c = 0; c < 4; c++)
      sh[c] = *(const f16x4*)(St + sidx(i, c * 256 + lane * 4));
    float num1[4][4];
    float s1 = 0.f;
#pragma unroll
    for (int c = 0; c < 4; c++)
#pragma unroll
      for (int j = 0; j < 4; j++) {
        const float s = (float)sh[c][j];
        const float nl = neglog(uv[c][j] + 1e-10f) + 1e-10f;
        num1[c][j] = __expf(s) * __builtin_amdgcn_rcpf(nl);
        s1 += num1[c][j];
      }
    s1 = wsum(s1);
    const float is1 = __builtin_amdgcn_rcpf(s1);
    float num2[4][4];
    float s2 = 0.f;
#pragma unroll
    for (int c = 0; c < 4; c++)
#pragma unroll
      for (int j = 0; j < 4; j++) {
        num2[c][j] = __expf((float)sh[c][j] + num1[c][j] * is1);  // TAU_1 = 1
        s2 += num2[c][j];
      }
    s2 = wsum(s2);
    const float is2 = __builtin_amdgcn_rcpf(s2);
#pragma unroll
    for (int c = 0; c < 4; c++) {
      f16x4 pw;
#pragma unroll
      for (int j = 0; j < 4; j++) pw[j] = (_Float16)(num2[c][j] * is2);
      *(f16x4*)(St + sidx(i, c * 256 + lane * 4)) = pw;
    }
  };

  // issue both rows' loads right before the barrier: the barrier's drain
  // overlaps with other waves finishing Phase A.
  ldrow(uA, i0);
  ldrow(uB, i0 + 1);
  __syncthreads();
  dorow(uA, i0);
  dorow(uB, i0 + 1);

  // pre-issue first V pair before the barrier (independent of LDS state)
  const int dg = wave & 3, half = wave >> 2;
  const _Float16* vrow = vp + (dg * 16 + lm) * 1024 + half * 512;  // V^T row d
  f16x8 vn0 = *(const f16x8*)(vrow + lq * 8);
  f16x8 vn1 = *(const f16x8*)(vrow + 32 + lq * 8);
  __syncthreads();

  // ---- Phase C: ctx[i][d] = sum_r P[i][r] * V[r][d], r-split by half ----
  f32x4 co0 = {0.f, 0.f, 0.f, 0.f}, co1 = {0.f, 0.f, 0.f, 0.f};
#pragma unroll 4
  for (int r0 = 0; r0 < 512; r0 += 64) {
    const f16x8 va0 = vn0, va1 = vn1;
    if (r0 < 448) {
      vn0 = *(const f16x8*)(vrow + r0 + 64 + lq * 8);
      vn1 = *(const f16x8*)(vrow + r0 + 96 + lq * 8);
    }
    const f16x8 pa0 = *(const f16x8*)(St + sidx(lm, half * 512 + r0 + lq * 8));
    const f16x8 pa1 = *(const f16x8*)(St + sidx(lm, half * 512 + r0 + 32 + lq * 8));
    co0 = __builtin_amdgcn_mfma_f32_16x16x32_f16(pa0, va0, co0, 0, 0, 0);
    co1 = __builtin_amdgcn_mfma_f32_16x16x32_f16(pa1, va1, co1, 0, 0, 0);
  }
  f32x4 co = co0 + co1;

  // combine halves: waves 4-7 park partials in LDS; waves 0-3 add + store
  if (wave >= 4) *(f32x4*)(&Cc[(dg * 64 + lane) * 4]) = co;
  __syncthreads();
  if (wave < 4) {
    co += *(const f32x4*)(&Cc[(dg * 64 + lane) * 4]);
#pragma unroll
    for (int rg = 0; rg < 4; rg++) {
      const int i = lq * 4 + rg;
      out[(size_t)(b * 1024 + L + i) * 1024 + h * 64 + dg * 16 + lm] = co[rg];
    }
  }
}

extern "C" void kernel_launch(void* const* d_in, const int* in_sizes, int n_in,
                              void* d_out, int out_size, void* d_ws, size_t ws_size,
                              hipStream_t stream) {
  const unsigned short* hidden = (const unsigned short*)d_in[0];
  const unsigned short* mask   = (const unsigned short*)d_in[1];
  const unsigned short* gum    = (const unsigned short*)d_in[2];
  const unsigned short* Wq     = (const unsigned short*)d_in[3];
  const unsigned short* bq     = (const unsigned short*)d_in[4];
  const unsigned short* Wk     = (const unsigned short*)d_in[5];
  const unsigned short* bk     = (const unsigned short*)d_in[6];
  const unsigned short* Wv     = (const unsigned short*)d_in[7];
  const unsigned short* bv     = (const unsigned short*)d_in[8];
  const unsigned short* de     = (const unsigned short*)d_in[9];

  _Float16* cvt16 = (_Float16*)((char*)d_ws + 256);              // 10 MB (dead after qkv)
  _Float16* q_ws  = cvt16 + (size_t)5 * 1024 * 1024;             // 4 MB
  _Float16* k_ws  = q_ws + (size_t)2 * 1024 * 1024;              // 4 MB
  _Float16* v_ws  = k_ws + (size_t)2 * 1024 * 1024;              // 4 MB
  _Float16* vT_ws = cvt16;             // reuse cvt16[0..2M) after qkv consumed it
  _Float16* e16   = cvt16 + (size_t)2 * 1024 * 1024;  // dead Wq slot, 256 KB
  float* out = (float*)d_out;

  cvt_inputs<<<dim3(2048, 4), 256, 0, stream>>>(hidden, Wq, Wk, Wv, gum, cvt16);
  qkv_gemm<<<dim3(32, 24), 256, 0, stream>>>(cvt16, bq, bk, bv, gum,
                                             q_ws, k_ws, v_ws);
  transpose_v_emb<<<dim3(16, 33), 256, 0, stream>>>(v_ws, vT_ws, de, gum, e16);
  attn_kernel<<<2048, 512, 0, stream>>>(q_ws, k_ws, vT_ws, e16, gum, mask, out);
}

// Round 6
// 321.486 us; speedup vs baseline: 1.0872x; 1.0872x over previous
//
#include <hip/hip_runtime.h>
#include <hip/hip_bf16.h>

typedef _Float16 f16x8 __attribute__((ext_vector_type(8)));
typedef _Float16 f16x4 __attribute__((ext_vector_type(4)));
typedef float f32x4 __attribute__((ext_vector_type(4)));
typedef int i32x4 __attribute__((ext_vector_type(4)));

__device__ __forceinline__ float bf2f(unsigned short u) {
  union { unsigned int i; float f; } x; x.i = ((unsigned int)u) << 16; return x.f;
}
// clamp-to-finite fp16 convert: any upstream bug shows finite, not NaN
__device__ __forceinline__ _Float16 h16(float f) {
  return (_Float16)fminf(fmaxf(f, -60000.f), 60000.f);
}

// accurate -log(u): series for u near 1 (1-u exact by Sterbenz there)
__device__ __forceinline__ float neglog(float u) {
  if (u > 0.99f) {
    const float d = 1.0f - u;
    return d + 0.5f * d * d + (1.0f / 3.0f) * d * d * d;
  }
  return -__logf(u);
}

// plain butterfly sum across 64 lanes
__device__ __forceinline__ float wsum(float v) {
#pragma unroll
  for (int off = 1; off < 64; off <<= 1) v += __shfl_xor(v, off, 64);
  return v;
}

// St row-keyed XOR swizzle: element idx ^ ((row&7)<<3) (byte bits 4-6).
// Stride-1024 rows -> Phase-C b128 column reads bank-balanced; Phase-B
// accesses are row-uniform (constant XOR per instr) = unchanged.
__device__ __forceinline__ int sidx(int row, int col) {
  return ((row) * 1024 + (col)) ^ (((row) & 7) << 3);
}

// Per-wave dtype detection: every wave reads the same first 64 bf16-shorts
// of gumbel (even indices) and ballots -> identical flag in all waves.
// 0 = bf16 inputs, 1 = fp32 inputs.
__device__ __forceinline__ int wave_flag(const unsigned short* __restrict__ g, int tid) {
  const float f = bf2f(g[(tid & 63) * 2]);
  const unsigned long long m = __ballot((f >= 8e-7f) && (f <= 1.0f));
  return (m == ~0ull) ? 0 : 1;
}

// ---------------------------------------------------------------------------
// Kernel 0: convert hidden + Wq/Wk/Wv to fp16 once.
// dst: [hid 2M | Wq 1M | Wk 1M | Wv 1M] halves.
// ---------------------------------------------------------------------------
__global__ __launch_bounds__(256) void cvt_inputs(
    const void* __restrict__ h, const void* __restrict__ wq,
    const void* __restrict__ wk, const void* __restrict__ wv,
    const unsigned short* __restrict__ gum, _Float16* __restrict__ dst)
{
  const int flg = wave_flag(gum, threadIdx.x);
  const int y = blockIdx.y;
  const int n = (y == 0) ? (2 * 1024 * 1024) : (1024 * 1024);
  const int idx = (blockIdx.x * 256 + threadIdx.x) * 4;
  if (idx >= n) return;
  const void* src = (y == 0) ? h : (y == 1) ? wq : (y == 2) ? wk : wv;
  const size_t base = (y == 0) ? 0 : (size_t)(2 * 1024 * 1024) + (size_t)(y - 1) * 1024 * 1024;
  f16x4 o;
  if (flg) {
    f32x4 v = *(const f32x4*)((const float*)src + idx);
#pragma unroll
    for (int j = 0; j < 4; j++) o[j] = h16(v[j]);
  } else {
    union { unsigned long long q; unsigned short u[4]; } ld;
    ld.q = *(const unsigned long long*)((const unsigned short*)src + idx);
#pragma unroll
    for (int j = 0; j < 4; j++) o[j] = h16(bf2f(ld.u[j]));
  }
  *(f16x4*)(dst + base + idx) = o;
}

// ---------------------------------------------------------------------------
// Kernel 1: QKV projection on pre-converted fp16. NT gemm 2048 x 3072 x 1024.
// ---------------------------------------------------------------------------
__global__ __launch_bounds__(256) void qkv_gemm(
    const _Float16* __restrict__ cvt,   // [hid | Wq | Wk | Wv]
    const unsigned short* __restrict__ bq, const unsigned short* __restrict__ bk,
    const unsigned short* __restrict__ bv,
    const unsigned short* __restrict__ gum,
    _Float16* __restrict__ q_ws, _Float16* __restrict__ k_ws,
    _Float16* __restrict__ v_ws)
{
  __shared__ _Float16 At[64][72];   // 64 x 64 fp16, +8 pad
  __shared__ _Float16 Bt[128][72];  // 128 x 64 fp16, +8 pad
  const int flg = wave_flag(gum, threadIdx.x);
  const int tn = blockIdx.x;        // 32 M-tiles of 64 rows
  const int to = blockIdx.y;        // 24 N-tiles of 128 cols over [q|k|v]
  const int mat = to >> 3;          // 0=q 1=k 2=v
  const int o0 = (to & 7) * 128;
  const _Float16* hid16 = cvt;
  const _Float16* W16 = cvt + (size_t)(2 * 1024 * 1024) + (size_t)mat * 1024 * 1024;
  const unsigned short* bias = (mat == 0) ? bq : (mat == 1) ? bk : bv;
  const float* biasf = (const float*)bias;
  const int tid = threadIdx.x;
  const int lane = tid & 63, wave = tid >> 6;
  const int wm = (wave >> 1) * 32, wn = (wave & 1) * 64;  // 2x2 quadrants 32x64
  const int lm = lane & 15, lq = lane >> 4;
  f32x4 acc[2][4] = {};

  for (int kc = 0; kc < 1024; kc += 64) {
    __syncthreads();
#pragma unroll
    for (int i = 0; i < 2; i++) {  // A: 64 rows x 8 chunks of 16B
      const int cid = i * 256 + tid;
      const int r = cid >> 3, c8 = cid & 7;
      *(i32x4*)(&At[r][c8 * 8]) =
          *(const i32x4*)(hid16 + (size_t)(tn * 64 + r) * 1024 + kc + c8 * 8);
    }
#pragma unroll
    for (int i = 0; i < 4; i++) {  // B: 128 rows x 8 chunks of 16B
      const int cid = i * 256 + tid;
      const int r = cid >> 3, c8 = cid & 7;
      *(i32x4*)(&Bt[r][c8 * 8]) =
          *(const i32x4*)(W16 + (size_t)(o0 + r) * 1024 + kc + c8 * 8);
    }
    __syncthreads();
    f16x8 af[2][2], bfr[4][2];
#pragma unroll
    for (int mt = 0; mt < 2; mt++)
#pragma unroll
      for (int k2 = 0; k2 < 2; k2++)
        af[mt][k2] = *(const f16x8*)(&At[wm + mt * 16 + lm][k2 * 32 + lq * 8]);
#pragma unroll
    for (int nt = 0; nt < 4; nt++)
#pragma unroll
      for (int k2 = 0; k2 < 2; k2++)
        bfr[nt][k2] = *(const f16x8*)(&Bt[wn + nt * 16 + lm][k2 * 32 + lq * 8]);
#pragma unroll
    for (int mt = 0; mt < 2; mt++)
#pragma unroll
      for (int nt = 0; nt < 4; nt++)
#pragma unroll
        for (int k2 = 0; k2 < 2; k2++)
          acc[mt][nt] = __builtin_amdgcn_mfma_f32_16x16x32_f16(
              af[mt][k2], bfr[nt][k2], acc[mt][nt], 0, 0, 0);
  }

  // epilogue: C/D layout col=lane&15, row=quad*4+reg
  _Float16* dst = (mat == 0) ? q_ws : (mat == 1) ? k_ws : v_ws;
#pragma unroll
  for (int nt = 0; nt < 4; nt++) {
    const int ol = o0 + wn + nt * 16 + lm;
    const float bias_v = flg ? biasf[ol] : bf2f(bias[ol]);
    const int hh = ol >> 6, dd = ol & 63;
#pragma unroll
    for (int mt = 0; mt < 2; mt++) {
#pragma unroll
      for (int rg = 0; rg < 4; rg++) {
        const int n = tn * 64 + wm + mt * 16 + lq * 4 + rg;  // b*1024+s
        const int b = n >> 10, s = n & 1023;
        dst[((size_t)(b * 16 + hh) * 1024 + s) * 64 + dd] = h16(acc[mt][nt][rg] + bias_v);
      }
    }
  }
}

// ---------------------------------------------------------------------------
// Kernel 2: transpose v [bh][s][64] -> vT [bh][64][s] via LDS 64x64 tiles,
// plus (grid y==32) dist_emb -> fp16 conversion.
// ---------------------------------------------------------------------------
__global__ __launch_bounds__(256) void transpose_v_emb(
    const _Float16* __restrict__ v_ws, _Float16* __restrict__ vT_ws,
    const void* __restrict__ de, const unsigned short* __restrict__ gum,
    _Float16* __restrict__ e16)
{
  __shared__ unsigned short Tt[64 * 66];
  const int tid = threadIdx.x;

  if (blockIdx.y == 32) {
    // dist_emb conversion: 2047*64 = 131008 halves = 32752 vec4 chunks
    const int flg = wave_flag(gum, tid);
    for (int c = blockIdx.x * 256 + tid; c < 32752; c += 16 * 256) {
      const int idx = c * 4;
      f16x4 o;
      if (flg) {
        f32x4 v = *(const f32x4*)((const float*)de + idx);
#pragma unroll
        for (int j = 0; j < 4; j++) o[j] = h16(v[j]);
      } else {
        union { unsigned long long q; unsigned short u[4]; } ld;
        ld.q = *(const unsigned long long*)((const unsigned short*)de + idx);
#pragma unroll
        for (int j = 0; j < 4; j++) o[j] = h16(bf2f(ld.u[j]));
      }
      *(f16x4*)(e16 + idx) = o;
    }
    return;
  }

  const int st = blockIdx.x;   // 16 s-tiles
  const int bh = blockIdx.y;   // 32
  const unsigned short* src = (const unsigned short*)(v_ws + (size_t)bh * 65536);
#pragma unroll
  for (int i = 0; i < 2; i++) {
    const int cid = i * 256 + tid;
    const int r = cid >> 3, c8 = cid & 7;   // row in tile, 8-half chunk
    union { i32x4 v; unsigned int w[4]; } ld;
    ld.v = *(const i32x4*)(src + (size_t)(st * 64 + r) * 64 + c8 * 8);
#pragma unroll
    for (int w = 0; w < 4; w++)
      *(unsigned int*)(&Tt[r * 66 + c8 * 8 + w * 2]) = ld.w[w];
  }
  __syncthreads();
  const int d = tid >> 2, sc = (tid & 3) * 16;
  unsigned short us[16];
#pragma unroll
  for (int j = 0; j < 16; j++) us[j] = Tt[(sc + j) * 66 + d];
  unsigned short* dst = (unsigned short*)(vT_ws + (size_t)bh * 65536 + (size_t)d * 1024 + st * 64 + sc);
#pragma unroll
  for (int w = 0; w < 4; w++)
    *(unsigned long long*)(dst + w * 4) = *(unsigned long long*)(us + w * 4);
}

// ---------------------------------------------------------------------------
// Kernel 3: fused scores + rel-pos + gumbel double-softmax + PV.
// One block (8 waves, 512 thr) per (b, h, 32-row l-tile). 1024 blocks.
//
// R5 post-mortem: occupancy 80% didn't help -> shared-resource bound.
// Theory: aggregate L2/L3 read traffic (K/E/V re-reads + gumbel stream
// evicting them). This version attacks traffic:
//  - 32-row tile: one K/V fragment feeds TWO Q row-groups -> K,V traffic
//    halves; E windows overlap by 16 rows -> 3 loads instead of 4 (x0.75).
//  - gumbel loads + out stores NONTEMPORAL: stop evicting K/V/E from L2.
//  - XCD swizzle: bh = (blk&7)*4+((blk>>3)&3) -> each XCD's L2 serves 4 bh
//    (1 MB K/V + 256 KB E working set).
//  - launch_bounds(512,4): 128 VGPR cap (R5's (512,8) forced 32 -> spills).
// LDS 72 KB -> 2 blocks/CU, 16 waves/CU (R5 proved that's not the binder).
// ---------------------------------------------------------------------------
__global__ __launch_bounds__(512, 4) void attn_kernel(
    const _Float16* __restrict__ q_ws, const _Float16* __restrict__ k_ws,
    const _Float16* __restrict__ vT_ws,
    const _Float16* __restrict__ e16,      // [2047][64] fp16
    const unsigned short* __restrict__ gumbel_u,
    const unsigned short* __restrict__ mask,
    float* __restrict__ out)
{
  __shared__ _Float16 St[32 * 1024];  // scores -> probs in place, 65536 B
  __shared__ float Cc[4 * 64 * 8];    // Phase-C partials (r-half 1), 8 KB
  const int tid = threadIdx.x, wave = tid >> 6, lane = tid & 63;
  const int flg = wave_flag(gumbel_u, tid);
  // XCD-locality swizzle: xcd = blk&7 (empirical RR); 4 bh per XCD.
  const int blk = blockIdx.x;                  // 0..1023
  const int bh = (blk & 7) * 4 + ((blk >> 3) & 3);
  const int lt = blk >> 5;                     // 0..31
  const int b = bh >> 4, h = bh & 15;
  const int L = lt * 32;
  const _Float16* qp = q_ws + (size_t)bh * 65536;
  const _Float16* kp = k_ws + (size_t)bh * 65536;
  const _Float16* vp = vT_ws + (size_t)bh * 65536;
  const unsigned short* up = gumbel_u + (size_t)bh * 1024 * 1024;
  const float* upf = (const float*)gumbel_u + (size_t)bh * 1024 * 1024;
  const float* maskf = (const float*)mask;
  const int lm = lane & 15, lq = lane >> 4;
  const int rr = wave * 16 + lm;         // this wave's score column in [0,128)

  // Q tile A-fragments: both 16-row groups, held for the whole block
  const f16x8 qa00 = *(const f16x8*)(qp + (L + lm) * 64 + lq * 8);
  const f16x8 qa01 = *(const f16x8*)(qp + (L + lm) * 64 + 32 + lq * 8);
  const f16x8 qa10 = *(const f16x8*)(qp + (L + 16 + lm) * 64 + lq * 8);
  const f16x8 qa11 = *(const f16x8*)(qp + (L + 16 + lm) * 64 + 32 + lq * 8);

  // ---- Phase A (no barriers): St = (Q.K^T + Q.E[l-r+1023])/8 + mask ----
  // 8 chunks of 128 cols (8 waves x 16). One K-frag feeds both row groups.
  // E windows w0=[b0,b0+16) w1=[b0+16,b0+32) w2=[b0+32,b0+48); lg0 uses
  // w0,w1; lg1 uses w1,w2 (16-row overlap shared). bpermute per lg as in R0.
#pragma unroll 2
  for (int R = 0; R < 1024; R += 128) {
    const _Float16* krow = kp + (R + rr) * 64;
    const f16x8 kb0 = *(const f16x8*)(krow + lq * 8);
    const f16x8 kb1 = *(const f16x8*)(krow + 32 + lq * 8);
    const int b0 = L - R - wave * 16 + 1008;     // in [0, 2000]
    const int re0 = b0 + lm;                     // <= 2015
    const int re1 = b0 + 16 + lm;                // <= 2031
    int re2 = b0 + 32 + lm;                      // <= 2047: clamp (o=31 unused)
    if (re2 > 2046) re2 = 2046;
    const f16x8 e0a = *(const f16x8*)(e16 + (size_t)re0 * 64 + lq * 8);
    const f16x8 e0b = *(const f16x8*)(e16 + (size_t)re0 * 64 + 32 + lq * 8);
    const f16x8 e1a = *(const f16x8*)(e16 + (size_t)re1 * 64 + lq * 8);
    const f16x8 e1b = *(const f16x8*)(e16 + (size_t)re1 * 64 + 32 + lq * 8);
    const f16x8 e2a = *(const f16x8*)(e16 + (size_t)re2 * 64 + lq * 8);
    const f16x8 e2b = *(const f16x8*)(e16 + (size_t)re2 * 64 + 32 + lq * 8);
    const float mval = flg ? maskf[b * 1024 + R + rr] : bf2f(mask[b * 1024 + R + rr]);

    f32x4 aqk0 = {0.f, 0.f, 0.f, 0.f}, aqk1 = {0.f, 0.f, 0.f, 0.f};
    aqk0 = __builtin_amdgcn_mfma_f32_16x16x32_f16(qa00, kb0, aqk0, 0, 0, 0);
    aqk0 = __builtin_amdgcn_mfma_f32_16x16x32_f16(qa01, kb1, aqk0, 0, 0, 0);
    aqk1 = __builtin_amdgcn_mfma_f32_16x16x32_f16(qa10, kb0, aqk1, 0, 0, 0);
    aqk1 = __builtin_amdgcn_mfma_f32_16x16x32_f16(qa11, kb1, aqk1, 0, 0, 0);
    f32x4 au00 = {0.f, 0.f, 0.f, 0.f}, au01 = {0.f, 0.f, 0.f, 0.f};
    f32x4 au10 = {0.f, 0.f, 0.f, 0.f}, au11 = {0.f, 0.f, 0.f, 0.f};
    au00 = __builtin_amdgcn_mfma_f32_16x16x32_f16(qa00, e0a, au00, 0, 0, 0);
    au00 = __builtin_amdgcn_mfma_f32_16x16x32_f16(qa01, e0b, au00, 0, 0, 0);
    au01 = __builtin_amdgcn_mfma_f32_16x16x32_f16(qa00, e1a, au01, 0, 0, 0);
    au01 = __builtin_amdgcn_mfma_f32_16x16x32_f16(qa01, e1b, au01, 0, 0, 0);
    au10 = __builtin_amdgcn_mfma_f32_16x16x32_f16(qa10, e1a, au10, 0, 0, 0);
    au10 = __builtin_amdgcn_mfma_f32_16x16x32_f16(qa11, e1b, au10, 0, 0, 0);
    au11 = __builtin_amdgcn_mfma_f32_16x16x32_f16(qa10, e2a, au11, 0, 0, 0);
    au11 = __builtin_amdgcn_mfma_f32_16x16x32_f16(qa11, e2b, au11, 0, 0, 0);

#pragma unroll
    for (int rg = 0; rg < 4; rg++) {
      const int o = lq * 4 + rg + 15 - lm;             // [0,30], same both lg
      const int idx = ((lane & 48) | (o & 15)) << 2;   // byte index for bpermute
      const float u00 = __int_as_float(
          __builtin_amdgcn_ds_bpermute(idx, __float_as_int(au00[rg])));
      const float u01 = __int_as_float(
          __builtin_amdgcn_ds_bpermute(idx, __float_as_int(au01[rg])));
      const float uv0 = (o >= 16) ? u01 : u00;
      St[sidx(lq * 4 + rg, R + rr)] = h16((aqk0[rg] + uv0) * 0.125f + mval);
      const float u10 = __int_as_float(
          __builtin_amdgcn_ds_bpermute(idx, __float_as_int(au10[rg])));
      const float u11 = __int_as_float(
          __builtin_amdgcn_ds_bpermute(idx, __float_as_int(au11[rg])));
      const float uv1 = (o >= 16) ? u11 : u10;
      St[sidx(16 + lq * 4 + rg, R + rr)] = h16((aqk1[rg] + uv1) * 0.125f + mval);
    }
  }

  // ---- Phase B: max-free double softmax, 4 rows/wave, 3-deep prefetch ----
  const int i0 = wave * 4;
  f32x4 uA[4], uB[4], uC[4];
  auto ldrow = [&](f32x4 (&dst)[4], int i) {
    if (flg) {
      const float* urf = upf + (size_t)(L + i) * 1024 + lane * 4;
#pragma unroll
      for (int c = 0; c < 4; c++)
        dst[c] = __builtin_nontemporal_load((const f32x4*)(urf + c * 256));
    } else {
      const unsigned short* ur = up + (size_t)(L + i) * 1024 + lane * 4;
#pragma unroll
      for (int c = 0; c < 4; c++) {
        union { unsigned long long q; unsigned short u[4]; } ld;
        ld.q = __builtin_nontemporal_load((const unsigned long long*)(ur + c * 256));
        f32x4 v;
#pragma unroll
        for (int j = 0; j < 4; j++) v[j] = bf2f(ld.u[j]);
        dst[c] = v;
      }
    }
  };
  auto dorow = [&](const f32x4 (&uv)[4], int i) {
    f16x4 sh[4];
#pragma unroll
    for (int c = 0; c < 4; c++)
      sh[c] = *(const f16x4*)(St + sidx(i, c * 256 + lane * 4));
    float num1[4][4];
    float s1 = 0.f;
#pragma unroll
    for (int c = 0; c < 4; c++)
#pragma unroll
      for (int j = 0; j < 4; j++) {
        const float s = (float)sh[c][j];
        const float nl = neglog(uv[c][j] + 1e-10f) + 1e-10f;
        num1[c][j] = __expf(s) * __builtin_amdgcn_rcpf(nl);
        s1 += num1[c][j];
      }
    s1 = wsum(s1);
    const float is1 = __builtin_amdgcn_rcpf(s1);
    float num2[4][4];
    float s2 = 0.f;
#pragma unroll
    for (int c = 0; c < 4; c++)
#pragma unroll
      for (int j = 0; j < 4; j++) {
        num2[c][j] = __expf((float)sh[c][j] + num1[c][j] * is1);  // TAU_1 = 1
        s2 += num2[c][j];
      }
    s2 = wsum(s2);
    const float is2 = __builtin_amdgcn_rcpf(s2);
#pragma unroll
    for (int c = 0; c < 4; c++) {
      f16x4 pw;
#pragma unroll
      for (int j = 0; j < 4; j++) pw[j] = (_Float16)(num2[c][j] * is2);
      *(f16x4*)(St + sidx(i, c * 256 + lane * 4)) = pw;
    }
  };

  // issue 3 rows right before the barrier (R4-proven placement/depth)
  ldrow(uA, i0);
  ldrow(uB, i0 + 1);
  ldrow(uC, i0 + 2);
  __syncthreads();
  dorow(uA, i0);
  ldrow(uA, i0 + 3);
  dorow(uB, i0 + 1);
  dorow(uC, i0 + 2);
  dorow(uA, i0 + 3);

  // pre-issue first V pair before the barrier
  const int dg = wave & 3, half = wave >> 2;
  const _Float16* vrow = vp + (dg * 16 + lm) * 1024 + half * 512;  // V^T row d
  f16x8 vn0 = *(const f16x8*)(vrow + lq * 8);
  f16x8 vn1 = *(const f16x8*)(vrow + 32 + lq * 8);
  __syncthreads();

  // ---- Phase C: ctx = P.V, r-split by half, one V-frag feeds both lg ----
  f32x4 c00 = {0.f, 0.f, 0.f, 0.f}, c01 = {0.f, 0.f, 0.f, 0.f};
  f32x4 c10 = {0.f, 0.f, 0.f, 0.f}, c11 = {0.f, 0.f, 0.f, 0.f};
#pragma unroll 4
  for (int r0 = 0; r0 < 512; r0 += 64) {
    const f16x8 va0 = vn0, va1 = vn1;
    if (r0 < 448) {
      vn0 = *(const f16x8*)(vrow + r0 + 64 + lq * 8);
      vn1 = *(const f16x8*)(vrow + r0 + 96 + lq * 8);
    }
    const int cb = half * 512 + r0;
    const f16x8 pa00 = *(const f16x8*)(St + sidx(lm, cb + lq * 8));
    const f16x8 pa01 = *(const f16x8*)(St + sidx(lm, cb + 32 + lq * 8));
    const f16x8 pa10 = *(const f16x8*)(St + sidx(16 + lm, cb + lq * 8));
    const f16x8 pa11 = *(const f16x8*)(St + sidx(16 + lm, cb + 32 + lq * 8));
    c00 = __builtin_amdgcn_mfma_f32_16x16x32_f16(pa00, va0, c00, 0, 0, 0);
    c01 = __builtin_amdgcn_mfma_f32_16x16x32_f16(pa01, va1, c01, 0, 0, 0);
    c10 = __builtin_amdgcn_mfma_f32_16x16x32_f16(pa10, va0, c10, 0, 0, 0);
    c11 = __builtin_amdgcn_mfma_f32_16x16x32_f16(pa11, va1, c11, 0, 0, 0);
  }
  f32x4 co0 = c00 + c01, co1 = c10 + c11;

  // combine halves: waves 4-7 park partials; waves 0-3 add + NT-store
  if (wave >= 4) {
    *(f32x4*)(&Cc[(dg * 64 + lane) * 8]) = co0;
    *(f32x4*)(&Cc[(dg * 64 + lane) * 8 + 4]) = co1;
  }
  __syncthreads();
  if (wave < 4) {
    co0 += *(const f32x4*)(&Cc[(dg * 64 + lane) * 8]);
    co1 += *(const f32x4*)(&Cc[(dg * 64 + lane) * 8 + 4]);
#pragma unroll
    for (int rg = 0; rg < 4; rg++) {
      const int i = lq * 4 + rg;
      __builtin_nontemporal_store(co0[rg],
          &out[(size_t)(b * 1024 + L + i) * 1024 + h * 64 + dg * 16 + lm]);
      __builtin_nontemporal_store(co1[rg],
          &out[(size_t)(b * 1024 + L + 16 + i) * 1024 + h * 64 + dg * 16 + lm]);
    }
  }
}

extern "C" void kernel_launch(void* const* d_in, const int* in_sizes, int n_in,
                              void* d_out, int out_size, void* d_ws, size_t ws_size,
                              hipStream_t stream) {
  const unsigned short* hidden = (const unsigned short*)d_in[0];
  const unsigned short* mask   = (const unsigned short*)d_in[1];
  const unsigned short* gum    = (const unsigned short*)d_in[2];
  const unsigned short* Wq     = (const unsigned short*)d_in[3];
  const unsigned short* bq     = (const unsigned short*)d_in[4];
  const unsigned short* Wk     = (const unsigned short*)d_in[5];
  const unsigned short* bk     = (const unsigned short*)d_in[6];
  const unsigned short* Wv     = (const unsigned short*)d_in[7];
  const unsigned short* bv     = (const unsigned short*)d_in[8];
  const unsigned short* de     = (const unsigned short*)d_in[9];

  _Float16* cvt16 = (_Float16*)((char*)d_ws + 256);              // 10 MB (dead after qkv)
  _Float16* q_ws  = cvt16 + (size_t)5 * 1024 * 1024;             // 4 MB
  _Float16* k_ws  = q_ws + (size_t)2 * 1024 * 1024;              // 4 MB
  _Float16* v_ws  = k_ws + (size_t)2 * 1024 * 1024;              // 4 MB
  _Float16* vT_ws = cvt16;             // reuse cvt16[0..2M) after qkv consumed it
  _Float16* e16   = cvt16 + (size_t)2 * 1024 * 1024;  // dead Wq slot, 256 KB
  float* out = (float*)d_out;

  cvt_inputs<<<dim3(2048, 4), 256, 0, stream>>>(hidden, Wq, Wk, Wv, gum, cvt16);
  qkv_gemm<<<dim3(32, 24), 256, 0, stream>>>(cvt16, bq, bk, bv, gum,
                                             q_ws, k_ws, v_ws);
  transpose_v_emb<<<dim3(16, 33), 256, 0, stream>>>(v_ws, vT_ws, de, gum, e16);
  attn_kernel<<<1024, 512, 0, stream>>>(q_ws, k_ws, vT_ws, e16, gum, mask, out);
}

// Round 7
// 320.914 us; speedup vs baseline: 1.0892x; 1.0018x over previous
//
#include <hip/hip_runtime.h>
#include <hip/hip_bf16.h>

typedef _Float16 f16x8 __attribute__((ext_vector_type(8)));
typedef _Float16 f16x4 __attribute__((ext_vector_type(4)));
typedef float f32x4 __attribute__((ext_vector_type(4)));
typedef int i32x4 __attribute__((ext_vector_type(4)));

__device__ __forceinline__ float bf2f(unsigned short u) {
  union { unsigned int i; float f; } x; x.i = ((unsigned int)u) << 16; return x.f;
}
// clamp-to-finite fp16 convert: any upstream bug shows finite, not NaN
__device__ __forceinline__ _Float16 h16(float f) {
  return (_Float16)fminf(fmaxf(f, -60000.f), 60000.f);
}

// accurate -log(u): series for u near 1 (1-u exact by Sterbenz there)
__device__ __forceinline__ float neglog(float u) {
  if (u > 0.99f) {
    const float d = 1.0f - u;
    return d + 0.5f * d * d + (1.0f / 3.0f) * d * d * d;
  }
  return -__logf(u);
}

// plain butterfly sum across 64 lanes
__device__ __forceinline__ float wsum(float v) {
#pragma unroll
  for (int off = 1; off < 64; off <<= 1) v += __shfl_xor(v, off, 64);
  return v;
}

// St row-keyed XOR swizzle: element idx ^ ((row&7)<<3) (byte bits 4-6).
__device__ __forceinline__ int sidx(int row, int col) {
  return ((row) * 1024 + (col)) ^ (((row) & 7) << 3);
}

// Per-wave dtype detection. 0 = bf16 inputs, 1 = fp32 inputs.
__device__ __forceinline__ int wave_flag(const unsigned short* __restrict__ g, int tid) {
  const float f = bf2f(g[(tid & 63) * 2]);
  const unsigned long long m = __ballot((f >= 8e-7f) && (f <= 1.0f));
  return (m == ~0ull) ? 0 : 1;
}

// ---------------------------------------------------------------------------
// Kernel 0: convert hidden + Wq/Wk/Wv to fp16 once.
// GRID-STRIDE, 1280 blocks (was 8192 blocks with 37% empty -> dispatch
// overhead per G11). dst: [hid 2M | Wq 1M | Wk 1M | Wv 1M] halves; dst
// element offset == c*4 because regions are concatenated in source order.
// ---------------------------------------------------------------------------
__global__ __launch_bounds__(256) void cvt_inputs(
    const void* __restrict__ h, const void* __restrict__ wq,
    const void* __restrict__ wk, const void* __restrict__ wv,
    const unsigned short* __restrict__ gum, _Float16* __restrict__ dst)
{
  const int flg = wave_flag(gum, threadIdx.x);
  // 5M halves = 1,310,720 vec4 chunks; 1280*256 threads x 4 iterations
  for (int c = blockIdx.x * 256 + threadIdx.x; c < 1310720; c += 1280 * 256) {
    const int c4 = c * 4;
    const void* src;
    int si;
    if (c4 < 2097152) { src = h; si = c4; }
    else {
      const int w = (c4 - 2097152) >> 20;        // 0,1,2
      si = (c4 - 2097152) & 1048575;
      src = (w == 0) ? wq : (w == 1) ? wk : wv;
    }
    f16x4 o;
    if (flg) {
      f32x4 v = *(const f32x4*)((const float*)src + si);
#pragma unroll
      for (int j = 0; j < 4; j++) o[j] = h16(v[j]);
    } else {
      union { unsigned long long q; unsigned short u[4]; } ld;
      ld.q = *(const unsigned long long*)((const unsigned short*)src + si);
#pragma unroll
      for (int j = 0; j < 4; j++) o[j] = h16(bf2f(ld.u[j]));
    }
    *(f16x4*)(dst + c4) = o;
  }
}

// ---------------------------------------------------------------------------
// Kernel 1: QKV projection on pre-converted fp16. NT gemm 2048 x 3072 x 1024.
// 64x128 tiles, BK=64, 768 blocks (3/CU).
// T3-minimum issue-early staging: loads for chunk kc+1 are issued into
// registers BEFORE chunk kc's MFMAs -> HBM latency hides under compute.
// ---------------------------------------------------------------------------
__global__ __launch_bounds__(256, 3) void qkv_gemm(
    const _Float16* __restrict__ cvt,   // [hid | Wq | Wk | Wv]
    const unsigned short* __restrict__ bq, const unsigned short* __restrict__ bk,
    const unsigned short* __restrict__ bv,
    const unsigned short* __restrict__ gum,
    _Float16* __restrict__ q_ws, _Float16* __restrict__ k_ws,
    _Float16* __restrict__ v_ws)
{
  __shared__ _Float16 At[64][72];   // 64 x 64 fp16, +8 pad
  __shared__ _Float16 Bt[128][72];  // 128 x 64 fp16, +8 pad
  const int flg = wave_flag(gum, threadIdx.x);
  const int tn = blockIdx.x;        // 32 M-tiles of 64 rows
  const int to = blockIdx.y;        // 24 N-tiles of 128 cols over [q|k|v]
  const int mat = to >> 3;          // 0=q 1=k 2=v
  const int o0 = (to & 7) * 128;
  const _Float16* hid16 = cvt;
  const _Float16* W16 = cvt + (size_t)(2 * 1024 * 1024) + (size_t)mat * 1024 * 1024;
  const unsigned short* bias = (mat == 0) ? bq : (mat == 1) ? bk : bv;
  const float* biasf = (const float*)bias;
  const int tid = threadIdx.x;
  const int lane = tid & 63, wave = tid >> 6;
  const int wm = (wave >> 1) * 32, wn = (wave & 1) * 64;  // 2x2 quadrants 32x64
  const int lm = lane & 15, lq = lane >> 4;
  f32x4 acc[2][4] = {};

  // per-thread staging addresses (row/chunk fixed; kc varies)
  const int ra0 = tid >> 3, ca = tid & 7;          // A rows: ra0, ra0+32
  const int rb0 = tid >> 3, cb = tid & 7;          // B rows: rb0 + 32*i
  i32x4 rA[2], rB[4];
  auto ldglobal = [&](int kc) {
#pragma unroll
    for (int i = 0; i < 2; i++)
      rA[i] = *(const i32x4*)(hid16 + (size_t)(tn * 64 + ra0 + i * 32) * 1024 + kc + ca * 8);
#pragma unroll
    for (int i = 0; i < 4; i++)
      rB[i] = *(const i32x4*)(W16 + (size_t)(o0 + rb0 + i * 32) * 1024 + kc + cb * 8);
  };

  ldglobal(0);
  for (int kc = 0; kc < 1024; kc += 64) {
    __syncthreads();   // previous chunk's frag reads complete
#pragma unroll
    for (int i = 0; i < 2; i++)
      *(i32x4*)(&At[ra0 + i * 32][ca * 8]) = rA[i];
#pragma unroll
    for (int i = 0; i < 4; i++)
      *(i32x4*)(&Bt[rb0 + i * 32][cb * 8]) = rB[i];
    __syncthreads();
    if (kc < 960) ldglobal(kc + 64);   // overlap next loads with MFMAs below

    f16x8 af[2][2], bfr[4][2];
#pragma unroll
    for (int mt = 0; mt < 2; mt++)
#pragma unroll
      for (int k2 = 0; k2 < 2; k2++)
        af[mt][k2] = *(const f16x8*)(&At[wm + mt * 16 + lm][k2 * 32 + lq * 8]);
#pragma unroll
    for (int nt = 0; nt < 4; nt++)
#pragma unroll
      for (int k2 = 0; k2 < 2; k2++)
        bfr[nt][k2] = *(const f16x8*)(&Bt[wn + nt * 16 + lm][k2 * 32 + lq * 8]);
#pragma unroll
    for (int mt = 0; mt < 2; mt++)
#pragma unroll
      for (int nt = 0; nt < 4; nt++)
#pragma unroll
        for (int k2 = 0; k2 < 2; k2++)
          acc[mt][nt] = __builtin_amdgcn_mfma_f32_16x16x32_f16(
              af[mt][k2], bfr[nt][k2], acc[mt][nt], 0, 0, 0);
  }

  // epilogue: C/D layout col=lane&15, row=quad*4+reg
  _Float16* dst = (mat == 0) ? q_ws : (mat == 1) ? k_ws : v_ws;
#pragma unroll
  for (int nt = 0; nt < 4; nt++) {
    const int ol = o0 + wn + nt * 16 + lm;
    const float bias_v = flg ? biasf[ol] : bf2f(bias[ol]);
    const int hh = ol >> 6, dd = ol & 63;
#pragma unroll
    for (int mt = 0; mt < 2; mt++) {
#pragma unroll
      for (int rg = 0; rg < 4; rg++) {
        const int n = tn * 64 + wm + mt * 16 + lq * 4 + rg;  // b*1024+s
        const int b = n >> 10, s = n & 1023;
        dst[((size_t)(b * 16 + hh) * 1024 + s) * 64 + dd] = h16(acc[mt][nt][rg] + bias_v);
      }
    }
  }
}

// ---------------------------------------------------------------------------
// Kernel 2: transpose v [bh][s][64] -> vT [bh][64][s] via LDS 64x64 tiles,
// plus (grid y==32) dist_emb -> fp16 conversion.
// ---------------------------------------------------------------------------
__global__ __launch_bounds__(256) void transpose_v_emb(
    const _Float16* __restrict__ v_ws, _Float16* __restrict__ vT_ws,
    const void* __restrict__ de, const unsigned short* __restrict__ gum,
    _Float16* __restrict__ e16)
{
  __shared__ unsigned short Tt[64 * 66];
  const int tid = threadIdx.x;

  if (blockIdx.y == 32) {
    // dist_emb conversion: 2047*64 = 131008 halves = 32752 vec4 chunks
    const int flg = wave_flag(gum, tid);
    for (int c = blockIdx.x * 256 + tid; c < 32752; c += 16 * 256) {
      const int idx = c * 4;
      f16x4 o;
      if (flg) {
        f32x4 v = *(const f32x4*)((const float*)de + idx);
#pragma unroll
        for (int j = 0; j < 4; j++) o[j] = h16(v[j]);
      } else {
        union { unsigned long long q; unsigned short u[4]; } ld;
        ld.q = *(const unsigned long long*)((const unsigned short*)de + idx);
#pragma unroll
        for (int j = 0; j < 4; j++) o[j] = h16(bf2f(ld.u[j]));
      }
      *(f16x4*)(e16 + idx) = o;
    }
    return;
  }

  const int st = blockIdx.x;   // 16 s-tiles
  const int bh = blockIdx.y;   // 32
  const unsigned short* src = (const unsigned short*)(v_ws + (size_t)bh * 65536);
#pragma unroll
  for (int i = 0; i < 2; i++) {
    const int cid = i * 256 + tid;
    const int r = cid >> 3, c8 = cid & 7;   // row in tile, 8-half chunk
    union { i32x4 v; unsigned int w[4]; } ld;
    ld.v = *(const i32x4*)(src + (size_t)(st * 64 + r) * 64 + c8 * 8);
#pragma unroll
    for (int w = 0; w < 4; w++)
      *(unsigned int*)(&Tt[r * 66 + c8 * 8 + w * 2]) = ld.w[w];
  }
  __syncthreads();
  const int d = tid >> 2, sc = (tid & 3) * 16;
  unsigned short us[16];
#pragma unroll
  for (int j = 0; j < 16; j++) us[j] = Tt[(sc + j) * 66 + d];
  unsigned short* dst = (unsigned short*)(vT_ws + (size_t)bh * 65536 + (size_t)d * 1024 + st * 64 + sc);
#pragma unroll
  for (int w = 0; w < 4; w++)
    *(unsigned long long*)(dst + w * 4) = *(unsigned long long*)(us + w * 4);
}

// ---------------------------------------------------------------------------
// Kernel 3: fused scores + rel-pos + gumbel double-softmax + PV.
// One block (8 waves, 512 thr) per (b, h, 32-row l-tile). 1024 blocks.
// R6 structure (traffic-halving 32-row tile, NT gumbel/out, XCD swizzle)
// + s_setprio(1) around MFMA clusters (T5: attn-positive, m191).
// ---------------------------------------------------------------------------
__global__ __launch_bounds__(512, 4) void attn_kernel(
    const _Float16* __restrict__ q_ws, const _Float16* __restrict__ k_ws,
    const _Float16* __restrict__ vT_ws,
    const _Float16* __restrict__ e16,      // [2047][64] fp16
    const unsigned short* __restrict__ gumbel_u,
    const unsigned short* __restrict__ mask,
    float* __restrict__ out)
{
  __shared__ _Float16 St[32 * 1024];  // scores -> probs in place, 65536 B
  __shared__ float Cc[4 * 64 * 8];    // Phase-C partials (r-half 1), 8 KB
  const int tid = threadIdx.x, wave = tid >> 6, lane = tid & 63;
  const int flg = wave_flag(gumbel_u, tid);
  // XCD-locality swizzle: xcd = blk&7; 4 bh per XCD.
  const int blk = blockIdx.x;                  // 0..1023
  const int bh = (blk & 7) * 4 + ((blk >> 3) & 3);
  const int lt = blk >> 5;                     // 0..31
  const int b = bh >> 4, h = bh & 15;
  const int L = lt * 32;
  const _Float16* qp = q_ws + (size_t)bh * 65536;
  const _Float16* kp = k_ws + (size_t)bh * 65536;
  const _Float16* vp = vT_ws + (size_t)bh * 65536;
  const unsigned short* up = gumbel_u + (size_t)bh * 1024 * 1024;
  const float* upf = (const float*)gumbel_u + (size_t)bh * 1024 * 1024;
  const float* maskf = (const float*)mask;
  const int lm = lane & 15, lq = lane >> 4;
  const int rr = wave * 16 + lm;         // this wave's score column in [0,128)

  // Q tile A-fragments: both 16-row groups, held for the whole block
  const f16x8 qa00 = *(const f16x8*)(qp + (L + lm) * 64 + lq * 8);
  const f16x8 qa01 = *(const f16x8*)(qp + (L + lm) * 64 + 32 + lq * 8);
  const f16x8 qa10 = *(const f16x8*)(qp + (L + 16 + lm) * 64 + lq * 8);
  const f16x8 qa11 = *(const f16x8*)(qp + (L + 16 + lm) * 64 + 32 + lq * 8);

  // ---- Phase A (no barriers): St = (Q.K^T + Q.E[l-r+1023])/8 + mask ----
#pragma unroll 2
  for (int R = 0; R < 1024; R += 128) {
    const _Float16* krow = kp + (R + rr) * 64;
    const f16x8 kb0 = *(const f16x8*)(krow + lq * 8);
    const f16x8 kb1 = *(const f16x8*)(krow + 32 + lq * 8);
    const int b0 = L - R - wave * 16 + 1008;     // in [0, 2000]
    const int re0 = b0 + lm;                     // <= 2015
    const int re1 = b0 + 16 + lm;                // <= 2031
    int re2 = b0 + 32 + lm;                      // <= 2047: clamp (o=31 unused)
    if (re2 > 2046) re2 = 2046;
    const f16x8 e0a = *(const f16x8*)(e16 + (size_t)re0 * 64 + lq * 8);
    const f16x8 e0b = *(const f16x8*)(e16 + (size_t)re0 * 64 + 32 + lq * 8);
    const f16x8 e1a = *(const f16x8*)(e16 + (size_t)re1 * 64 + lq * 8);
    const f16x8 e1b = *(const f16x8*)(e16 + (size_t)re1 * 64 + 32 + lq * 8);
    const f16x8 e2a = *(const f16x8*)(e16 + (size_t)re2 * 64 + lq * 8);
    const f16x8 e2b = *(const f16x8*)(e16 + (size_t)re2 * 64 + 32 + lq * 8);
    const float mval = flg ? maskf[b * 1024 + R + rr] : bf2f(mask[b * 1024 + R + rr]);

    __builtin_amdgcn_s_setprio(1);
    f32x4 aqk0 = {0.f, 0.f, 0.f, 0.f}, aqk1 = {0.f, 0.f, 0.f, 0.f};
    aqk0 = __builtin_amdgcn_mfma_f32_16x16x32_f16(qa00, kb0, aqk0, 0, 0, 0);
    aqk0 = __builtin_amdgcn_mfma_f32_16x16x32_f16(qa01, kb1, aqk0, 0, 0, 0);
    aqk1 = __builtin_amdgcn_mfma_f32_16x16x32_f16(qa10, kb0, aqk1, 0, 0, 0);
    aqk1 = __builtin_amdgcn_mfma_f32_16x16x32_f16(qa11, kb1, aqk1, 0, 0, 0);
    f32x4 au00 = {0.f, 0.f, 0.f, 0.f}, au01 = {0.f, 0.f, 0.f, 0.f};
    f32x4 au10 = {0.f, 0.f, 0.f, 0.f}, au11 = {0.f, 0.f, 0.f, 0.f};
    au00 = __builtin_amdgcn_mfma_f32_16x16x32_f16(qa00, e0a, au00, 0, 0, 0);
    au00 = __builtin_amdgcn_mfma_f32_16x16x32_f16(qa01, e0b, au00, 0, 0, 0);
    au01 = __builtin_amdgcn_mfma_f32_16x16x32_f16(qa00, e1a, au01, 0, 0, 0);
    au01 = __builtin_amdgcn_mfma_f32_16x16x32_f16(qa01, e1b, au01, 0, 0, 0);
    au10 = __builtin_amdgcn_mfma_f32_16x16x32_f16(qa10, e1a, au10, 0, 0, 0);
    au10 = __builtin_amdgcn_mfma_f32_16x16x32_f16(qa11, e1b, au10, 0, 0, 0);
    au11 = __builtin_amdgcn_mfma_f32_16x16x32_f16(qa10, e2a, au11, 0, 0, 0);
    au11 = __builtin_amdgcn_mfma_f32_16x16x32_f16(qa11, e2b, au11, 0, 0, 0);
    __builtin_amdgcn_s_setprio(0);

#pragma unroll
    for (int rg = 0; rg < 4; rg++) {
      const int o = lq * 4 + rg + 15 - lm;             // [0,30], same both lg
      const int idx = ((lane & 48) | (o & 15)) << 2;   // byte index for bpermute
      const float u00 = __int_as_float(
          __builtin_amdgcn_ds_bpermute(idx, __float_as_int(au00[rg])));
      const float u01 = __int_as_float(
          __builtin_amdgcn_ds_bpermute(idx, __float_as_int(au01[rg])));
      const float uv0 = (o >= 16) ? u01 : u00;
      St[sidx(lq * 4 + rg, R + rr)] = h16((aqk0[rg] + uv0) * 0.125f + mval);
      const float u10 = __int_as_float(
          __builtin_amdgcn_ds_bpermute(idx, __float_as_int(au10[rg])));
      const float u11 = __int_as_float(
          __builtin_amdgcn_ds_bpermute(idx, __float_as_int(au11[rg])));
      const float uv1 = (o >= 16) ? u11 : u10;
      St[sidx(16 + lq * 4 + rg, R + rr)] = h16((aqk1[rg] + uv1) * 0.125f + mval);
    }
  }

  // ---- Phase B: max-free double softmax, 4 rows/wave, 3-deep prefetch ----
  const int i0 = wave * 4;
  f32x4 uA[4], uB[4], uC[4];
  auto ldrow = [&](f32x4 (&dst)[4], int i) {
    if (flg) {
      const float* urf = upf + (size_t)(L + i) * 1024 + lane * 4;
#pragma unroll
      for (int c = 0; c < 4; c++)
        dst[c] = __builtin_nontemporal_load((const f32x4*)(urf + c * 256));
    } else {
      const unsigned short* ur = up + (size_t)(L + i) * 1024 + lane * 4;
#pragma unroll
      for (int c = 0; c < 4; c++) {
        union { unsigned long long q; unsigned short u[4]; } ld;
        ld.q = __builtin_nontemporal_load((const unsigned long long*)(ur + c * 256));
        f32x4 v;
#pragma unroll
        for (int j = 0; j < 4; j++) v[j] = bf2f(ld.u[j]);
        dst[c] = v;
      }
    }
  };
  auto dorow = [&](const f32x4 (&uv)[4], int i) {
    f16x4 sh[4];
#pragma unroll
    for (int c = 0; c < 4; c++)
      sh[c] = *(const f16x4*)(St + sidx(i, c * 256 + lane * 4));
    float num1[4][4];
    float s1 = 0.f;
#pragma unroll
    for (int c = 0; c < 4; c++)
#pragma unroll
      for (int j = 0; j < 4; j++) {
        const float s = (float)sh[c][j];
        const float nl = neglog(uv[c][j] + 1e-10f) + 1e-10f;
        num1[c][j] = __expf(s) * __builtin_amdgcn_rcpf(nl);
        s1 += num1[c][j];
      }
    s1 = wsum(s1);
    const float is1 = __builtin_amdgcn_rcpf(s1);
    float num2[4][4];
    float s2 = 0.f;
#pragma unroll
    for (int c = 0; c < 4; c++)
#pragma unroll
      for (int j = 0; j < 4; j++) {
        num2[c][j] = __expf((float)sh[c][j] + num1[c][j] * is1);  // TAU_1 = 1
        s2 += num2[c][j];
      }
    s2 = wsum(s2);
    const float is2 = __builtin_amdgcn_rcpf(s2);
#pragma unroll
    for (int c = 0; c < 4; c++) {
      f16x4 pw;
#pragma unroll
      for (int j = 0; j < 4; j++) pw[j] = (_Float16)(num2[c][j] * is2);
      *(f16x4*)(St + sidx(i, c * 256 + lane * 4)) = pw;
    }
  };

  // issue 3 rows right before the barrier (R4-proven placement/depth)
  ldrow(uA, i0);
  ldrow(uB, i0 + 1);
  ldrow(uC, i0 + 2);
  __syncthreads();
  dorow(uA, i0);
  ldrow(uA, i0 + 3);
  dorow(uB, i0 + 1);
  dorow(uC, i0 + 2);
  dorow(uA, i0 + 3);

  // pre-issue first V pair before the barrier
  const int dg = wave & 3, half = wave >> 2;
  const _Float16* vrow = vp + (dg * 16 + lm) * 1024 + half * 512;  // V^T row d
  f16x8 vn0 = *(const f16x8*)(vrow + lq * 8);
  f16x8 vn1 = *(const f16x8*)(vrow + 32 + lq * 8);
  __syncthreads();

  // ---- Phase C: ctx = P.V, r-split by half, one V-frag feeds both lg ----
  f32x4 c00 = {0.f, 0.f, 0.f, 0.f}, c01 = {0.f, 0.f, 0.f, 0.f};
  f32x4 c10 = {0.f, 0.f, 0.f, 0.f}, c11 = {0.f, 0.f, 0.f, 0.f};
#pragma unroll 4
  for (int r0 = 0; r0 < 512; r0 += 64) {
    const f16x8 va0 = vn0, va1 = vn1;
    if (r0 < 448) {
      vn0 = *(const f16x8*)(vrow + r0 + 64 + lq * 8);
      vn1 = *(const f16x8*)(vrow + r0 + 96 + lq * 8);
    }
    const int cb = half * 512 + r0;
    const f16x8 pa00 = *(const f16x8*)(St + sidx(lm, cb + lq * 8));
    const f16x8 pa01 = *(const f16x8*)(St + sidx(lm, cb + 32 + lq * 8));
    const f16x8 pa10 = *(const f16x8*)(St + sidx(16 + lm, cb + lq * 8));
    const f16x8 pa11 = *(const f16x8*)(St + sidx(16 + lm, cb + 32 + lq * 8));
    __builtin_amdgcn_s_setprio(1);
    c00 = __builtin_amdgcn_mfma_f32_16x16x32_f16(pa00, va0, c00, 0, 0, 0);
    c01 = __builtin_amdgcn_mfma_f32_16x16x32_f16(pa01, va1, c01, 0, 0, 0);
    c10 = __builtin_amdgcn_mfma_f32_16x16x32_f16(pa10, va0, c10, 0, 0, 0);
    c11 = __builtin_amdgcn_mfma_f32_16x16x32_f16(pa11, va1, c11, 0, 0, 0);
    __builtin_amdgcn_s_setprio(0);
  }
  f32x4 co0 = c00 + c01, co1 = c10 + c11;

  // combine halves: waves 4-7 park partials; waves 0-3 add + NT-store
  if (wave >= 4) {
    *(f32x4*)(&Cc[(dg * 64 + lane) * 8]) = co0;
    *(f32x4*)(&Cc[(dg * 64 + lane) * 8 + 4]) = co1;
  }
  __syncthreads();
  if (wave < 4) {
    co0 += *(const f32x4*)(&Cc[(dg * 64 + lane) * 8]);
    co1 += *(const f32x4*)(&Cc[(dg * 64 + lane) * 8 + 4]);
#pragma unroll
    for (int rg = 0; rg < 4; rg++) {
      const int i = lq * 4 + rg;
      __builtin_nontemporal_store(co0[rg],
          &out[(size_t)(b * 1024 + L + i) * 1024 + h * 64 + dg * 16 + lm]);
      __builtin_nontemporal_store(co1[rg],
          &out[(size_t)(b * 1024 + L + 16 + i) * 1024 + h * 64 + dg * 16 + lm]);
    }
  }
}

extern "C" void kernel_launch(void* const* d_in, const int* in_sizes, int n_in,
                              void* d_out, int out_size, void* d_ws, size_t ws_size,
                              hipStream_t stream) {
  const unsigned short* hidden = (const unsigned short*)d_in[0];
  const unsigned short* mask   = (const unsigned short*)d_in[1];
  const unsigned short* gum    = (const unsigned short*)d_in[2];
  const unsigned short* Wq     = (const unsigned short*)d_in[3];
  const unsigned short* bq     = (const unsigned short*)d_in[4];
  const unsigned short* Wk     = (const unsigned short*)d_in[5];
  const unsigned short* bk     = (const unsigned short*)d_in[6];
  const unsigned short* Wv     = (const unsigned short*)d_in[7];
  const unsigned short* bv     = (const unsigned short*)d_in[8];
  const unsigned short* de     = (const unsigned short*)d_in[9];

  _Float16* cvt16 = (_Float16*)((char*)d_ws + 256);              // 10 MB (dead after qkv)
  _Float16* q_ws  = cvt16 + (size_t)5 * 1024 * 1024;             // 4 MB
  _Float16* k_ws  = q_ws + (size_t)2 * 1024 * 1024;              // 4 MB
  _Float16* v_ws  = k_ws + (size_t)2 * 1024 * 1024;              // 4 MB
  _Float16* vT_ws = cvt16;             // reuse cvt16[0..2M) after qkv consumed it
  _Float16* e16   = cvt16 + (size_t)2 * 1024 * 1024;  // dead Wq slot, 256 KB
  float* out = (float*)d_out;

  cvt_inputs<<<1280, 256, 0, stream>>>(hidden, Wq, Wk, Wv, gum, cvt16);
  qkv_gemm<<<dim3(32, 24), 256, 0, stream>>>(cvt16, bq, bk, bv, gum,
                                             q_ws, k_ws, v_ws);
  transpose_v_emb<<<dim3(16, 33), 256, 0, stream>>>(v_ws, vT_ws, de, gum, e16);
  attn_kernel<<<1024, 512, 0, stream>>>(q_ws, k_ws, vT_ws, e16, gum, mask, out);
}